// Round 2
// baseline (242.246 us; speedup 1.0000x reference)
//
#include <hip/hip_runtime.h>
#include <hip/hip_bf16.h>

// SelfAttention2D: B=4, C=256, H=W=64, N=4096, Cqk=32.
// Flash-style fused attention, bf16 MFMA 16x16x32, fp32 accum.
// Key ideas this revision:
//  - S computed TRANSPOSED (mfma(K,Q)) so P rows land on l16 -> P packs
//    in-lane into A-frag slot order (key dim permuted; permutation also
//    applied to V's storage so the contraction stays exact).
//  - P staged via ONE ds_write_b128 / read via ds_read_b128, XOR-swizzled
//    (bandwidth-minimal, conflict-free).
//  - exp2 with log2(e) folded into Q at projection; RTZ v_perm bf16 pack
//    (uniform relative bias cancels in softmax ratio).
//  - 512-thread attn blocks (8 waves/CU), 64-key KV tile (64 barriers).

typedef __attribute__((ext_vector_type(8))) short s8v;  // 8 bf16 (MFMA A/B frag)
typedef __attribute__((ext_vector_type(4))) float f4v;  // MFMA C/D frag

#define NPIX 4096
#define CIN 256
#define DQK 32

#if __has_builtin(__builtin_amdgcn_exp2f)
#define EXP2(x) __builtin_amdgcn_exp2f(x)
#else
#define EXP2(x) exp2f(x)
#endif

static __device__ __forceinline__ unsigned short f2bf(float f) {
    union { float f; unsigned int u; } v; v.f = f;
    unsigned int r = v.u + 0x7FFF + ((v.u >> 16) & 1);   // RTNE
    return (unsigned short)(r >> 16);
}
static __device__ __forceinline__ unsigned int fbits(float f) {
    union { float f; unsigned int u; } v; v.f = f; return v.u;
}

// ---------------------------------------------------------------------------
// Kernel 1: pack Wq/Wk/Wv -> bf16 Wall[320][256], biases -> fp32 ball[320].
__global__ void wcast_kernel(const float* __restrict__ Wq, const float* __restrict__ bq,
                             const float* __restrict__ Wk, const float* __restrict__ bk,
                             const float* __restrict__ Wv, const float* __restrict__ bv,
                             unsigned short* __restrict__ Wall, float* __restrict__ ball) {
    int row = blockIdx.x;
    int t = threadIdx.x;
    const float* src; const float* bsrc;
    if (row < 32)       { src = Wq + row * 256;        bsrc = bq + row; }
    else if (row < 64)  { src = Wk + (row - 32) * 256; bsrc = bk + (row - 32); }
    else                { src = Wv + (row - 64) * 256; bsrc = bv + (row - 64); }
    Wall[row * 256 + t] = f2bf(src[t]);
    if (t == 0) ball[row] = bsrc[0];
}

// ---------------------------------------------------------------------------
// Kernel 2: x[b][c][n] fp32 -> xT[b][n][c] bf16 (64x64 LDS tile transpose).
__global__ void tcast_kernel(const float* __restrict__ x, unsigned short* __restrict__ xT) {
    __shared__ unsigned short tile[64][65];
    int bidx = blockIdx.x;
    int b    = bidx >> 8;
    int cblk = (bidx >> 6) & 3;
    int nblk = bidx & 63;
    int t = threadIdx.x;
    int c0 = cblk * 64, n0 = nblk * 64;
    const float* xb = x + (size_t)b * CIN * NPIX;
    #pragma unroll
    for (int p = 0; p < 4; p++) {
        int cl = p * 16 + (t >> 4);
        int nl = (t & 15) * 4;
        float4 v = *(const float4*)(xb + (size_t)(c0 + cl) * NPIX + n0 + nl);
        tile[cl][nl + 0] = f2bf(v.x);
        tile[cl][nl + 1] = f2bf(v.y);
        tile[cl][nl + 2] = f2bf(v.z);
        tile[cl][nl + 3] = f2bf(v.w);
    }
    __syncthreads();
    unsigned short* xTb = xT + (size_t)b * NPIX * CIN;
    #pragma unroll
    for (int p = 0; p < 4; p++) {
        int nl = p * 16 + (t >> 4);
        int cl = (t & 15) * 4;
        ushort4 wv;
        wv.x = tile[cl + 0][nl];
        wv.y = tile[cl + 1][nl];
        wv.z = tile[cl + 2][nl];
        wv.w = tile[cl + 3][nl];
        *(ushort4*)(xTb + (size_t)(n0 + nl) * CIN + c0 + cl) = wv;
    }
}

// ---------------------------------------------------------------------------
// Kernel 3: projection GEMM. grid = 4b x 64nblk x 2 oc-halves = 512 blocks.
// Each block: 64 n-rows (4 waves x 16), B-frags held in registers, loops 10
// ocblks in interleaved pairs (2 indep MFMA chains).
// oc 0..31 -> Q (scaled by log2 e), 32..63 -> K, 64..319 -> Vt (KEY-PERMUTED).
__global__ __launch_bounds__(256, 2)
void proj_kernel(const unsigned short* __restrict__ xT,
                 const unsigned short* __restrict__ Wall,
                 const float* __restrict__ ball,
                 unsigned short* __restrict__ Q,
                 unsigned short* __restrict__ K,
                 unsigned short* __restrict__ Vt) {
    int b    = blockIdx.x >> 7;
    int rem  = blockIdx.x & 127;
    int nblk = rem >> 1;
    int h    = rem & 1;
    int w    = threadIdx.x >> 6;
    int lane = threadIdx.x & 63;
    int l16 = lane & 15, quad = lane >> 4;
    int n = nblk * 64 + w * 16 + l16;

    const unsigned short* brow = xT + (size_t)(b * NPIX + n) * CIN + quad * 8;
    s8v bfr[8];
    #pragma unroll
    for (int kk = 0; kk < 8; kk++) bfr[kk] = *(const s8v*)(brow + kk * 32);

    // V permutation target index for this lane's n (within its 32-group)
    int kl = n & 31;
    int slot = ((kl & 15) >> 2) * 8 + ((kl >> 4) & 1) * 4 + (kl & 3);
    int np = (n & ~31) | slot;

    #pragma unroll
    for (int p = 0; p < 5; p++) {
        int ob0 = h * 10 + 2 * p;
        const unsigned short* a0row = Wall + (size_t)(ob0 * 16 + l16) * CIN + quad * 8;
        const unsigned short* a1row = a0row + 16 * CIN;
        f4v acc0 = {0.f, 0.f, 0.f, 0.f}, acc1 = {0.f, 0.f, 0.f, 0.f};
        #pragma unroll
        for (int kk = 0; kk < 8; kk++) {
            s8v a0 = *(const s8v*)(a0row + kk * 32);
            s8v a1 = *(const s8v*)(a1row + kk * 32);
            acc0 = __builtin_amdgcn_mfma_f32_16x16x32_bf16(a0, bfr[kk], acc0, 0, 0, 0);
            acc1 = __builtin_amdgcn_mfma_f32_16x16x32_bf16(a1, bfr[kk], acc1, 0, 0, 0);
        }
        #pragma unroll
        for (int half = 0; half < 2; half++) {
            int ob = ob0 + half;
            f4v acc = half ? acc1 : acc0;
            if (ob < 2) {            // Q rows, fold log2(e) for exp2 softmax
                #pragma unroll
                for (int r = 0; r < 4; r++) {
                    int oc = ob * 16 + quad * 4 + r;
                    Q[(size_t)(b * NPIX + n) * DQK + oc] =
                        f2bf((acc[r] + ball[oc]) * 1.44269504f);
                }
            } else if (ob < 4) {     // K rows
                #pragma unroll
                for (int r = 0; r < 4; r++) {
                    int oc = ob * 16 + quad * 4 + r;
                    K[(size_t)(b * NPIX + n) * DQK + (oc - 32)] = f2bf(acc[r] + ball[oc]);
                }
            } else {                 // V rows, key-permuted n
                #pragma unroll
                for (int r = 0; r < 4; r++) {
                    int oc = ob * 16 + quad * 4 + r;
                    Vt[(size_t)(b * CIN + (oc - 64)) * NPIX + np] = f2bf(acc[r] + ball[oc]);
                }
            }
        }
    }
}

// ---------------------------------------------------------------------------
// Kernel 4: flash attention. Block = 64 q-rows, 512 threads (8 waves),
// KV tile = 64 keys/iter (1 barrier). Wave w: S for (rowtile w>>1, key
// chunk w&1 [2 16-key tiles]); PV for rowtiles {2*(w>>2),2*(w>>2)+1} x
// cols [(w&3)*64, +64).
__global__ __launch_bounds__(512, 2)
void attn_kernel(const unsigned short* __restrict__ Q,
                 const unsigned short* __restrict__ K,
                 const unsigned short* __restrict__ Vt,
                 const float* __restrict__ gamma,
                 float* __restrict__ out) {
    // [buf][rt][row(16) x 128B]: row = 8 x 16B units, unit v=(c*4+quad),
    // stored at v^(l16&7) -> conflict-free b128 r/w.
    __shared__ unsigned int ldsP[2][4][16 * 32];
    __shared__ float ldsL[4][2][16];

    int idx = blockIdx.x;
    int b      = (idx & 7) >> 1;                    // XCD-pair affinity per batch
    int rowblk = ((idx >> 3) << 1) | (idx & 1);

    int lane = threadIdx.x & 63;
    int w    = threadIdx.x >> 6;
    int l16 = lane & 15, quad = lane >> 4;

    int rt_s = w >> 1;   // S rowtile
    int ck   = w & 1;    // S key chunk (16-key tiles {2ck, 2ck+1})
    int rg   = w >> 2;   // PV rowtile pair
    int cg   = w & 3;    // PV col group

    const unsigned short* Kb = K + (size_t)b * NPIX * DQK;
    const unsigned short* Vb = Vt + (size_t)b * CIN * NPIX;

    // Q frag (B operand of S^T): rows of rt_s
    const s8v qfrag = *(const s8v*)(Q + (size_t)(b * NPIX + rowblk * 64 + rt_s * 16 + l16) * DQK + quad * 8);

    const unsigned short* kp0 = Kb + (size_t)(ck * 32 + l16) * DQK + quad * 8;
    const unsigned short* kp1 = kp0 + 16 * DQK;

    const unsigned short* vp0 = Vb + (size_t)(cg * 64 +  0 + l16) * NPIX + quad * 8;
    const unsigned short* vp1 = Vb + (size_t)(cg * 64 + 16 + l16) * NPIX + quad * 8;
    const unsigned short* vp2 = Vb + (size_t)(cg * 64 + 32 + l16) * NPIX + quad * 8;
    const unsigned short* vp3 = Vb + (size_t)(cg * 64 + 48 + l16) * NPIX + quad * 8;

    f4v O[2][4];
    #pragma unroll
    for (int i = 0; i < 2; i++)
        #pragma unroll
        for (int j = 0; j < 4; j++) O[i][j] = (f4v){0.f, 0.f, 0.f, 0.f};
    float lsum = 0.f;

    // write slot: row l16, unit (ck*4+quad)^(l16&7)
    unsigned int* wP = &ldsP[0][rt_s][l16 * 32 + ((ck * 4 + quad) ^ (l16 & 7)) * 4];

    for (int kv = 0; kv < NPIX; kv += 64) {
        int it = (kv >> 6) & 1;
        s8v k0 = *(const s8v*)(kp0 + (size_t)kv * DQK);
        s8v k1 = *(const s8v*)(kp1 + (size_t)kv * DQK);
        s8v vfr[4][2];
        vfr[0][0] = *(const s8v*)(vp0 + kv);  vfr[0][1] = *(const s8v*)(vp0 + kv + 32);
        vfr[1][0] = *(const s8v*)(vp1 + kv);  vfr[1][1] = *(const s8v*)(vp1 + kv + 32);
        vfr[2][0] = *(const s8v*)(vp2 + kv);  vfr[2][1] = *(const s8v*)(vp2 + kv + 32);
        vfr[3][0] = *(const s8v*)(vp3 + kv);  vfr[3][1] = *(const s8v*)(vp3 + kv + 32);

        // S^T = mfma(K, Q): lane holds S[row=l16][key = kt*16 + quad*4 + r]
        f4v s0 = {0.f, 0.f, 0.f, 0.f}, s1 = {0.f, 0.f, 0.f, 0.f};
        s0 = __builtin_amdgcn_mfma_f32_16x16x32_bf16(k0, qfrag, s0, 0, 0, 0);
        s1 = __builtin_amdgcn_mfma_f32_16x16x32_bf16(k1, qfrag, s1, 0, 0, 0);

        float p00 = EXP2(s0[0]), p01 = EXP2(s0[1]), p02 = EXP2(s0[2]), p03 = EXP2(s0[3]);
        float p10 = EXP2(s1[0]), p11 = EXP2(s1[1]), p12 = EXP2(s1[2]), p13 = EXP2(s1[3]);
        lsum += ((p00 + p01) + (p02 + p03)) + ((p10 + p11) + (p12 + p13));

        // RTZ bf16 pack into A-frag slot order (bias cancels in softmax ratio)
        uint4 pk;
        pk.x = __builtin_amdgcn_perm(fbits(p01), fbits(p00), 0x07060302);
        pk.y = __builtin_amdgcn_perm(fbits(p03), fbits(p02), 0x07060302);
        pk.z = __builtin_amdgcn_perm(fbits(p11), fbits(p10), 0x07060302);
        pk.w = __builtin_amdgcn_perm(fbits(p13), fbits(p12), 0x07060302);
        *(uint4*)(wP + it * (4 * 16 * 32)) = pk;   // one ds_write_b128

        __syncthreads();

        s8v pa[2][2];
        #pragma unroll
        for (int i = 0; i < 2; i++) {
            int rt = rg * 2 + i;
            #pragma unroll
            for (int c = 0; c < 2; c++) {
                int vsw = ((c * 4 + quad) ^ (l16 & 7)) * 4;
                pa[i][c] = *(const s8v*)(&ldsP[it][rt][l16 * 32 + vsw]);
            }
        }
        #pragma unroll
        for (int i = 0; i < 2; i++) {
            #pragma unroll
            for (int ct = 0; ct < 4; ct++) {
                O[i][ct] = __builtin_amdgcn_mfma_f32_16x16x32_bf16(pa[i][0], vfr[ct][0], O[i][ct], 0, 0, 0);
                O[i][ct] = __builtin_amdgcn_mfma_f32_16x16x32_bf16(pa[i][1], vfr[ct][1], O[i][ct], 0, 0, 0);
            }
        }
    }

    // row-sum partials: reduce over quads, publish per (rt_s, chunk ck)
    float v = lsum;
    v += __shfl_xor(v, 16);
    v += __shfl_xor(v, 32);
    if (lane < 16) ldsL[rt_s][ck][lane] = v;
    __syncthreads();

    float g = gamma[0];
    #pragma unroll
    for (int i = 0; i < 2; i++) {
        int rt = rg * 2 + i;
        float rL[4];
        #pragma unroll
        for (int r = 0; r < 4; r++)
            rL[r] = g / (ldsL[rt][0][quad * 4 + r] + ldsL[rt][1][quad * 4 + r]);
        #pragma unroll
        for (int ct = 0; ct < 4; ct++) {
            int col = cg * 64 + ct * 16 + l16;
            float4 vv;
            vv.x = O[i][ct][0] * rL[0];
            vv.y = O[i][ct][1] * rL[1];
            vv.z = O[i][ct][2] * rL[2];
            vv.w = O[i][ct][3] * rL[3];
            *(float4*)(out + (size_t)(b * CIN + col) * NPIX + rowblk * 64 + rt * 16 + quad * 4) = vv;
        }
    }
}

// ---------------------------------------------------------------------------
extern "C" void kernel_launch(void* const* d_in, const int* in_sizes, int n_in,
                              void* d_out, int out_size, void* d_ws, size_t ws_size,
                              hipStream_t stream) {
    const float* x     = (const float*)d_in[0];
    const float* Wq    = (const float*)d_in[1];
    const float* bq    = (const float*)d_in[2];
    const float* Wk    = (const float*)d_in[3];
    const float* bk    = (const float*)d_in[4];
    const float* Wv    = (const float*)d_in[5];
    const float* bv    = (const float*)d_in[6];
    const float* gamma = (const float*)d_in[7];
    float* out = (float*)d_out;

    char* p = (char*)d_ws;
    unsigned short* xT   = (unsigned short*)p; p += (size_t)4 * NPIX * CIN * 2;   // 8 MB
    unsigned short* Qb   = (unsigned short*)p; p += (size_t)4 * NPIX * DQK * 2;   // 1 MB
    unsigned short* Kb   = (unsigned short*)p; p += (size_t)4 * NPIX * DQK * 2;   // 1 MB
    unsigned short* Vt   = (unsigned short*)p; p += (size_t)4 * CIN * NPIX * 2;   // 8 MB
    unsigned short* Wall = (unsigned short*)p; p += (size_t)320 * 256 * 2;
    float*          ball = (float*)p;          p += (size_t)320 * 4;

    wcast_kernel<<<320, 256, 0, stream>>>(Wq, bq, Wk, bk, Wv, bv, Wall, ball);
    tcast_kernel<<<1024, 256, 0, stream>>>(x, xT);
    proj_kernel<<<512, 256, 0, stream>>>(xT, Wall, ball, Qb, Kb, Vt);
    attn_kernel<<<256, 512, 0, stream>>>(Qb, Kb, Vt, gamma, out);
}